// Round 1
// baseline (2931.388 us; speedup 1.0000x reference)
//
#include <hip/hip_runtime.h>

#define NN 262144   // rows (embeddings)
#define DD 128      // dim
#define KK 512      // clusters
#define NITER 5

// LDS strides (floats): padded so b128 reads stay 16B-aligned and conflicts ~2-way
#define SE 68       // E^T tile stride  (64 rows + pad)
#define SC 260      // C^T tile stride  (256 cols + pad)
#define SS 65       // argmax scratch stride

// ---------------------------------------------------------------------------
// Kernel A: assignment. Per block: 64 rows x all 512 clusters (2 chunks of 256).
// Thread grid 8(ty: rows) x 32(tx: cols); 8x8 fp32 register tile per thread.
// ---------------------------------------------------------------------------
__global__ __launch_bounds__(256) void assign_kernel(
    const float* __restrict__ E, const float* __restrict__ C,
    int* __restrict__ assignv)
{
    __shared__ float smem[32 * SE + 32 * SC];   // 41984 B
    float* ET = smem;                  // [32][SE]  d-major E tile
    float* CT = smem + 32 * SE;        // [32][SC]  d-major C tile
    // argmax scratch overlays staging buffers (used after compute, resync'd)
    float* sval = smem;                // [32 tx][SS] -> [tx*SS + row]
    int*   sidx = ((int*)smem) + 32 * SS;

    __shared__ float bestv[64];
    __shared__ int   bestk[64];

    const int tid = threadIdx.x;
    const int tx  = tid & 31;
    const int ty  = tid >> 5;
    const int r0  = blockIdx.x * 64;

    for (int chunk = 0; chunk < 2; ++chunk) {
        const int k0 = chunk * 256;
        float acc[8][8];
#pragma unroll
        for (int i = 0; i < 8; ++i)
#pragma unroll
            for (int j = 0; j < 8; ++j) acc[i][j] = 0.f;

        for (int sub = 0; sub < 4; ++sub) {
            const int d0 = sub * 32;
            __syncthreads();   // previous compute / scratch readers done
            // stage E^T: 64 rows x 32 d  (512 float4, 2 per thread)
#pragma unroll
            for (int it = 0; it < 2; ++it) {
                int idx = tid + it * 256;
                int r = idx >> 3, q = idx & 7;
                float4 v = *(const float4*)&E[(r0 + r) * DD + d0 + q * 4];
                ET[(q * 4 + 0) * SE + r] = v.x;
                ET[(q * 4 + 1) * SE + r] = v.y;
                ET[(q * 4 + 2) * SE + r] = v.z;
                ET[(q * 4 + 3) * SE + r] = v.w;
            }
            // stage C^T: 256 cols x 32 d (2048 float4, 8 per thread)
#pragma unroll
            for (int it = 0; it < 8; ++it) {
                int idx = tid + it * 256;
                int k = idx >> 3, q = idx & 7;
                float4 v = *(const float4*)&C[(k0 + k) * DD + d0 + q * 4];
                CT[(q * 4 + 0) * SC + k] = v.x;
                CT[(q * 4 + 1) * SC + k] = v.y;
                CT[(q * 4 + 2) * SC + k] = v.z;
                CT[(q * 4 + 3) * SC + k] = v.w;
            }
            __syncthreads();
#pragma unroll 4
            for (int d = 0; d < 32; ++d) {
                float4 a0 = *(const float4*)&ET[d * SE + ty * 8];
                float4 a1 = *(const float4*)&ET[d * SE + ty * 8 + 4];
                float4 b0 = *(const float4*)&CT[d * SC + tx * 8];
                float4 b1 = *(const float4*)&CT[d * SC + tx * 8 + 4];
                float ra[8] = {a0.x, a0.y, a0.z, a0.w, a1.x, a1.y, a1.z, a1.w};
                float rb[8] = {b0.x, b0.y, b0.z, b0.w, b1.x, b1.y, b1.z, b1.w};
#pragma unroll
                for (int i = 0; i < 8; ++i)
#pragma unroll
                    for (int j = 0; j < 8; ++j)
                        acc[i][j] = fmaf(ra[i], rb[j], acc[i][j]);
            }
        }
        __syncthreads();   // done reading ET/CT; scratch overlay is safe now

        // per-thread argmax over its 8 cols (ascending j => first-max tiebreak)
#pragma unroll
        for (int i = 0; i < 8; ++i) {
            float bv = acc[i][0]; int bj = 0;
#pragma unroll
            for (int j = 1; j < 8; ++j)
                if (acc[i][j] > bv) { bv = acc[i][j]; bj = j; }
            int row = ty * 8 + i;
            sval[tx * SS + row] = bv;
            sidx[tx * SS + row] = k0 + tx * 8 + bj;
        }
        __syncthreads();
        // cross-tx merge per row (ascending tx = ascending k, strict >)
        if (tid < 64) {
            float bv = sval[tid]; int bi = sidx[tid];
            for (int t = 1; t < 32; ++t) {
                float v = sval[t * SS + tid];
                if (v > bv) { bv = v; bi = sidx[t * SS + tid]; }
            }
            if (chunk == 0 || bv > bestv[tid]) { bestv[tid] = bv; bestk[tid] = bi; }
        }
        // next chunk's leading __syncthreads protects scratch reuse
    }
    if (tid < 64) assignv[r0 + tid] = bestk[tid];
}

// ---------------------------------------------------------------------------
// Kernel B: M-step + normalize. One block per cluster (exclusive ownership,
// no global atomics). 4 waves scan quarters of assign[]; per-lane register
// accumulators (2 dims/lane), cross-wave reduce, mean, L2-normalize in place.
// ---------------------------------------------------------------------------
__global__ __launch_bounds__(256) void update_kernel(
    const float* __restrict__ E, const int* __restrict__ assignv,
    float* __restrict__ C)
{
    const int k = blockIdx.x;
    __shared__ float acc[4][DD];
    __shared__ int   cnts[4];
    __shared__ float red[4];

    const int tid  = threadIdx.x;
    const int w    = tid >> 6;
    const int lane = tid & 63;

    float a0 = 0.f, a1 = 0.f;
    int cnt = 0;
    const int per_wave = NN / 4;
    const int base = w * per_wave;

    for (int it = 0; it < per_wave / 256; ++it) {
        const int off = base + it * 256;
        int4 as = *(const int4*)&assignv[off + lane * 4];
        int av[4] = {as.x, as.y, as.z, as.w};
#pragma unroll
        for (int c = 0; c < 4; ++c) {
            unsigned long long m = __ballot(av[c] == k);
            cnt += (int)__popcll(m);
            while (m) {
                int b = __ffsll((long long)m) - 1;
                m &= m - 1;
                int r = off + b * 4 + c;
                float2 v = *(const float2*)&E[r * DD + lane * 2];
                a0 += v.x;
                a1 += v.y;
            }
        }
    }
    acc[w][lane * 2]     = a0;
    acc[w][lane * 2 + 1] = a1;
    if (lane == 0) cnts[w] = cnt;
    __syncthreads();

    float m = 0.f;
    const int ctot = cnts[0] + cnts[1] + cnts[2] + cnts[3];
    if (tid < DD) {
        float s = acc[0][tid] + acc[1][tid] + acc[2][tid] + acc[3][tid];
        m = (ctot > 0) ? s / (float)ctot : C[k * DD + tid];
    }
    float sq = m * m;   // waves 2,3 contribute 0
#pragma unroll
    for (int o = 32; o > 0; o >>= 1) sq += __shfl_down(sq, o, 64);
    if (lane == 0) red[w] = sq;
    __syncthreads();
    if (tid < DD) {
        float nrm = sqrtf(red[0] + red[1]);
        nrm = fmaxf(nrm, 1e-12f);
        C[k * DD + tid] = m / nrm;
    }
}

// ---------------------------------------------------------------------------
// Finalize: convert assign ints (stored in d_out head) to float32 in place.
// Centroids were computed directly into the d_out tail.
// ---------------------------------------------------------------------------
__global__ void finalize_kernel(float* __restrict__ out)
{
    int i = blockIdx.x * 256 + threadIdx.x;
    if (i < NN) {
        int a = ((const int*)out)[i];
        out[i] = (float)a;
    }
}

extern "C" void kernel_launch(void* const* d_in, const int* in_sizes, int n_in,
                              void* d_out, int out_size, void* d_ws, size_t ws_size,
                              hipStream_t stream)
{
    (void)in_sizes; (void)n_in; (void)out_size; (void)d_ws; (void)ws_size;

    const float* E  = (const float*)d_in[0];
    const float* C0 = (const float*)d_in[1];
    // num_iters (d_in[2]) is a fixed scalar = 5; hardcoded (graph-safe).

    float* out     = (float*)d_out;
    float* C       = out + NN;        // centroids live in d_out tail
    int*   assignv = (int*)out;       // assign ints live in d_out head

    hipMemcpyAsync(C, C0, (size_t)KK * DD * sizeof(float),
                   hipMemcpyDeviceToDevice, stream);

    for (int it = 0; it < NITER; ++it) {
        assign_kernel<<<NN / 64, 256, 0, stream>>>(E, C, assignv);
        update_kernel<<<KK, 256, 0, stream>>>(E, assignv, C);
    }
    finalize_kernel<<<(NN + 255) / 256, 256, 0, stream>>>(out);
}

// Round 3
// 2902.112 us; speedup vs baseline: 1.0101x; 1.0101x over previous
//
#include <hip/hip_runtime.h>

#define NN 262144   // rows (embeddings)
#define DD 128      // dim
#define KK 512      // clusters
#define NITER 5

// LDS strides (floats). SE/SC chosen so total = 40960 B exactly -> 4 blocks/CU.
#define SE 64       // E^T tile stride
#define SC 256      // C^T tile stride
#define SS 65       // argmax scratch stride (padded, conflict-free)

// ---------------------------------------------------------------------------
// Kernel A: assignment. Per block: 64 rows x all 512 clusters (2 chunks of 256).
// 8x8 fp32 register tile per thread; B cols are {4tx..4tx+3, 128+4tx..+3} so
// LDS B reads are 32 contiguous float4 = all 32 banks (conflict-free; the
// 64-lane wave reads each address twice = 2-way, which is free per m136).
// Round-1 measured 88 VGPR for this structure -> (256,4) bound (cap 128) is
// safe, and 4 blocks x 40960 B = exactly 160 KiB LDS/CU.
// ---------------------------------------------------------------------------
__global__ __launch_bounds__(256, 4) void assign_kernel(
    const float* __restrict__ E, const float* __restrict__ C,
    int* __restrict__ assignv)
{
    __shared__ float smem[32 * SE + 32 * SC];   // 10240 floats = 40960 B
    float* ET = smem;                  // [32 d][SE]
    float* CT = smem + 32 * SE;        // [32 d][SC]
    // argmax scratch overlays staging (resync'd before reuse)
    float* sval = smem;                // [32 tx][SS]
    int*   sidx = ((int*)smem) + 32 * SS;

    const int tid = threadIdx.x;
    const int tx  = tid & 31;
    const int ty  = tid >> 5;
    const int r0  = blockIdx.x * 64;

    float bbv = 0.f;   // running best (valid in tid<64 only)
    int   bbk = 0;

    for (int chunk = 0; chunk < 2; ++chunk) {
        const int k0 = chunk * 256;
        float acc[8][8];
#pragma unroll
        for (int i = 0; i < 8; ++i)
#pragma unroll
            for (int j = 0; j < 8; ++j) acc[i][j] = 0.f;

        for (int sub = 0; sub < 4; ++sub) {
            const int d0 = sub * 32;
            __syncthreads();   // previous compute / scratch readers done
            // stage E^T: 64 rows x 32 d (512 float4, 2 per thread)
#pragma unroll
            for (int it = 0; it < 2; ++it) {
                int idx = tid + it * 256;
                int r = idx >> 3, q = idx & 7;
                float4 v = *(const float4*)&E[(r0 + r) * DD + d0 + q * 4];
                ET[(q * 4 + 0) * SE + r] = v.x;
                ET[(q * 4 + 1) * SE + r] = v.y;
                ET[(q * 4 + 2) * SE + r] = v.z;
                ET[(q * 4 + 3) * SE + r] = v.w;
            }
            // stage C^T: 256 cols x 32 d (2048 float4, 8 per thread)
#pragma unroll
            for (int it = 0; it < 8; ++it) {
                int idx = tid + it * 256;
                int k = idx >> 3, q = idx & 7;
                float4 v = *(const float4*)&C[(k0 + k) * DD + d0 + q * 4];
                CT[(q * 4 + 0) * SC + k] = v.x;
                CT[(q * 4 + 1) * SC + k] = v.y;
                CT[(q * 4 + 2) * SC + k] = v.z;
                CT[(q * 4 + 3) * SC + k] = v.w;
            }
            __syncthreads();
#pragma unroll 4
            for (int d = 0; d < 32; ++d) {
                float4 a0 = *(const float4*)&ET[d * SE + ty * 8];
                float4 a1 = *(const float4*)&ET[d * SE + ty * 8 + 4];
                float4 b0 = *(const float4*)&CT[d * SC + tx * 4];        // cols 4tx..4tx+3
                float4 b1 = *(const float4*)&CT[d * SC + 128 + tx * 4];  // cols 128+4tx..
                float ra[8] = {a0.x, a0.y, a0.z, a0.w, a1.x, a1.y, a1.z, a1.w};
                float rb[8] = {b0.x, b0.y, b0.z, b0.w, b1.x, b1.y, b1.z, b1.w};
#pragma unroll
                for (int i = 0; i < 8; ++i)
#pragma unroll
                    for (int j = 0; j < 8; ++j)
                        acc[i][j] = fmaf(ra[i], rb[j], acc[i][j]);
            }
        }
        __syncthreads();   // all compute done; overlay scratch is safe

        // per-thread argmax over its 8 cols. j=0..3 -> k0+4tx+j, j=4..7 ->
        // k0+128+4tx+(j-4): ascending k within thread => strict > is
        // first-occurrence correct here.
#pragma unroll
        for (int i = 0; i < 8; ++i) {
            float bv = acc[i][0]; int bj = 0;
#pragma unroll
            for (int j = 1; j < 8; ++j)
                if (acc[i][j] > bv) { bv = acc[i][j]; bj = j; }
            int row = ty * 8 + i;
            int gk = k0 + ((bj < 4) ? (tx * 4 + bj) : (128 + tx * 4 + (bj - 4)));
            sval[tx * SS + row] = bv;
            sidx[tx * SS + row] = gk;
        }
        __syncthreads();
        // cross-tx merge per row. Column ranges interleave across tx, so ties
        // MUST break on lower global index (numpy first-occurrence).
        if (tid < 64) {
            float bv = sval[tid]; int bi = sidx[tid];
            for (int t = 1; t < 32; ++t) {
                float v = sval[t * SS + tid];
                int   x = sidx[t * SS + tid];
                if (v > bv || (v == bv && x < bi)) { bv = v; bi = x; }
            }
            if (chunk == 0 || bv > bbv || (bv == bbv && bi < bbk)) {
                bbv = bv; bbk = bi;
            }
        }
        // next chunk's first __syncthreads protects scratch before restage
    }
    if (tid < 64) assignv[r0 + tid] = bbk;
}

// ---------------------------------------------------------------------------
// M-step + normalize (round-1 verified version; no d_ws usage).
// One block per cluster (exclusive ownership, no global atomics). 4 waves
// scan quarters of assign[]; matching rows loaded cooperatively (2 dims/lane),
// cross-wave reduce, mean (keep old centroid if empty), L2-normalize in place.
// ---------------------------------------------------------------------------
__global__ __launch_bounds__(256) void update_kernel(
    const float* __restrict__ E, const int* __restrict__ assignv,
    float* __restrict__ C)
{
    const int k = blockIdx.x;
    __shared__ float acc[4][DD];
    __shared__ int   cnts[4];
    __shared__ float red[4];

    const int tid  = threadIdx.x;
    const int w    = tid >> 6;
    const int lane = tid & 63;

    float a0 = 0.f, a1 = 0.f;
    int cnt = 0;
    const int per_wave = NN / 4;
    const int base = w * per_wave;

    for (int it = 0; it < per_wave / 256; ++it) {
        const int off = base + it * 256;
        int4 as = *(const int4*)&assignv[off + lane * 4];
        int av[4] = {as.x, as.y, as.z, as.w};
#pragma unroll
        for (int c = 0; c < 4; ++c) {
            unsigned long long m = __ballot(av[c] == k);
            cnt += (int)__popcll(m);
            while (m) {
                int b = __ffsll((long long)m) - 1;
                m &= m - 1;
                int r = off + b * 4 + c;
                float2 v = *(const float2*)&E[r * DD + lane * 2];
                a0 += v.x; a1 += v.y;
            }
        }
    }
    acc[w][lane * 2]     = a0;
    acc[w][lane * 2 + 1] = a1;
    if (lane == 0) cnts[w] = cnt;
    __syncthreads();

    float m = 0.f;
    const int ctot = cnts[0] + cnts[1] + cnts[2] + cnts[3];
    if (tid < DD) {
        float s = acc[0][tid] + acc[1][tid] + acc[2][tid] + acc[3][tid];
        m = (ctot > 0) ? s / (float)ctot : C[k * DD + tid];
    }
    float sq = m * m;   // waves 2,3 contribute 0
#pragma unroll
    for (int o = 32; o > 0; o >>= 1) sq += __shfl_down(sq, o, 64);
    if (lane == 0) red[w] = sq;
    __syncthreads();
    if (tid < DD) {
        float nrm = fmaxf(sqrtf(red[0] + red[1]), 1e-12f);
        C[k * DD + tid] = m / nrm;
    }
}

// ---------------------------------------------------------------------------
// Finalize: convert assign ints (stored in d_out head) to float32 in place.
// Centroids were computed directly into the d_out tail.
// ---------------------------------------------------------------------------
__global__ void finalize_kernel(float* __restrict__ out)
{
    int i = blockIdx.x * 256 + threadIdx.x;
    if (i < NN) {
        int a = ((const int*)out)[i];
        out[i] = (float)a;
    }
}

extern "C" void kernel_launch(void* const* d_in, const int* in_sizes, int n_in,
                              void* d_out, int out_size, void* d_ws, size_t ws_size,
                              hipStream_t stream)
{
    (void)in_sizes; (void)n_in; (void)out_size; (void)d_ws; (void)ws_size;

    const float* E  = (const float*)d_in[0];
    const float* C0 = (const float*)d_in[1];
    // num_iters (d_in[2]) is a fixed scalar = 5; hardcoded (graph-safe).

    float* out     = (float*)d_out;
    float* C       = out + NN;        // centroids in d_out tail
    int*   assignv = (int*)out;       // assign ints in d_out head

    hipMemcpyAsync(C, C0, (size_t)KK * DD * sizeof(float),
                   hipMemcpyDeviceToDevice, stream);

    for (int it = 0; it < NITER; ++it) {
        assign_kernel<<<NN / 64, 256, 0, stream>>>(E, C, assignv);
        update_kernel<<<KK, 256, 0, stream>>>(E, assignv, C);
    }
    finalize_kernel<<<(NN + 255) / 256, 256, 0, stream>>>(out);
}

// Round 4
// 2288.961 us; speedup vs baseline: 1.2807x; 1.2679x over previous
//
#include <hip/hip_runtime.h>

#define NN 262144   // rows (embeddings)
#define DD 128      // dim
#define KK 512      // clusters
#define NITER 5

// LDS strides (floats). ≡4 (mod 32) so b128 reads stay 16B-aligned while
// staging-write banks get the q-term spread (4-way instead of 8-way).
#define SE 132      // E^T tile stride (128 rows + 4 pad)
#define SC 260      // C^T tile stride (256 cols + 4 pad)
#define SS 129      // argmax scratch stride (conflict-free)

// workspace layout for fast M-step
#define WS_A16_BYTES   (NN * 2)                       // u16 assigns
#define WS_SUMS_OFF    (WS_A16_BYTES)                 // 2048 x 128 f32 partials
#define WS_CNTS_OFF    (WS_SUMS_OFF + 2048 * DD * 4)  // 2048 i32 counts
#define WS_NEEDED      (WS_CNTS_OFF + 2048 * 4)

// ---------------------------------------------------------------------------
// Kernel A: assignment. Per block: 128 rows x all 512 clusters (2 chunks of
// 256). Thread tile 16 rows x 8 cols (acc = 128 VGPR). A-fragment reads are
// 2-address broadcasts (ty-pairs), B-fragment reads 2-way dup'd contiguous
// float4 (free). VALU ~256 cyc/d/wave vs LDS ~34 cyc/d/wave -> VALU-bound.
// ---------------------------------------------------------------------------
__global__ __launch_bounds__(256, 2) void assign_kernel(
    const float* __restrict__ E, const float* __restrict__ C,
    int* __restrict__ assignv, unsigned short* __restrict__ assign16)
{
    __shared__ float smem[32 * SE + 32 * SC];   // 12544 floats = 50176 B
    float* ET = smem;                  // [32 d][SE]
    float* CT = smem + 32 * SE;        // [32 d][SC]
    // argmax scratch overlays staging (resync'd before reuse)
    float* sval = smem;                // [32 tx][SS]
    int*   sidx = ((int*)smem) + 32 * SS;

    const int tid = threadIdx.x;
    const int tx  = tid & 31;
    const int ty  = tid >> 5;          // 0..7 -> rows ty*16..ty*16+15
    const int r0  = blockIdx.x * 128;

    float bbv = 0.f;   // running best (valid in tid<128 only)
    int   bbk = 0;

    for (int chunk = 0; chunk < 2; ++chunk) {
        const int k0 = chunk * 256;
        float acc[16][8];
#pragma unroll
        for (int i = 0; i < 16; ++i)
#pragma unroll
            for (int j = 0; j < 8; ++j) acc[i][j] = 0.f;

        for (int sub = 0; sub < 4; ++sub) {
            const int d0 = sub * 32;
            __syncthreads();   // previous compute / scratch readers done
            // stage E^T: 128 rows x 32 d (1024 float4, 4 per thread)
#pragma unroll
            for (int it = 0; it < 4; ++it) {
                int idx = tid + it * 256;
                int r = idx >> 3, q = idx & 7;
                float4 v = *(const float4*)&E[(r0 + r) * DD + d0 + q * 4];
                ET[(q * 4 + 0) * SE + r] = v.x;
                ET[(q * 4 + 1) * SE + r] = v.y;
                ET[(q * 4 + 2) * SE + r] = v.z;
                ET[(q * 4 + 3) * SE + r] = v.w;
            }
            // stage C^T: 256 cols x 32 d (2048 float4, 8 per thread)
#pragma unroll
            for (int it = 0; it < 8; ++it) {
                int idx = tid + it * 256;
                int k = idx >> 3, q = idx & 7;
                float4 v = *(const float4*)&C[(k0 + k) * DD + d0 + q * 4];
                CT[(q * 4 + 0) * SC + k] = v.x;
                CT[(q * 4 + 1) * SC + k] = v.y;
                CT[(q * 4 + 2) * SC + k] = v.z;
                CT[(q * 4 + 3) * SC + k] = v.w;
            }
            __syncthreads();
#pragma unroll 4
            for (int d = 0; d < 32; ++d) {
                float4 a0 = *(const float4*)&ET[d * SE + ty * 16];
                float4 a1 = *(const float4*)&ET[d * SE + ty * 16 + 4];
                float4 a2 = *(const float4*)&ET[d * SE + ty * 16 + 8];
                float4 a3 = *(const float4*)&ET[d * SE + ty * 16 + 12];
                float4 b0 = *(const float4*)&CT[d * SC + tx * 4];        // cols 4tx..
                float4 b1 = *(const float4*)&CT[d * SC + 128 + tx * 4];  // cols 128+4tx..
                float ra[16] = {a0.x, a0.y, a0.z, a0.w, a1.x, a1.y, a1.z, a1.w,
                                a2.x, a2.y, a2.z, a2.w, a3.x, a3.y, a3.z, a3.w};
                float rb[8]  = {b0.x, b0.y, b0.z, b0.w, b1.x, b1.y, b1.z, b1.w};
#pragma unroll
                for (int i = 0; i < 16; ++i)
#pragma unroll
                    for (int j = 0; j < 8; ++j)
                        acc[i][j] = fmaf(ra[i], rb[j], acc[i][j]);
            }
        }
        __syncthreads();   // all compute done; overlay scratch is safe

        // per-thread argmax over its 8 cols per row. j=0..3 -> k0+4tx+j,
        // j=4..7 -> k0+128+4tx+(j-4): ascending k within thread, so strict >
        // is first-occurrence correct here.
#pragma unroll
        for (int i = 0; i < 16; ++i) {
            float bv = acc[i][0]; int bj = 0;
#pragma unroll
            for (int j = 1; j < 8; ++j)
                if (acc[i][j] > bv) { bv = acc[i][j]; bj = j; }
            int row = ty * 16 + i;
            int gk = k0 + ((bj < 4) ? (tx * 4 + bj) : (128 + tx * 4 + (bj - 4)));
            sval[tx * SS + row] = bv;
            sidx[tx * SS + row] = gk;
        }
        __syncthreads();
        // cross-tx merge per row. Column ranges interleave across tx, so ties
        // MUST break on lower global index (numpy first-occurrence).
        if (tid < 128) {
            float bv = sval[tid]; int bi = sidx[tid];
            for (int t = 1; t < 32; ++t) {
                float v = sval[t * SS + tid];
                int   x = sidx[t * SS + tid];
                if (v > bv || (v == bv && x < bi)) { bv = v; bi = x; }
            }
            if (chunk == 0 || bv > bbv || (bv == bbv && bi < bbk)) {
                bbv = bv; bbk = bi;
            }
        }
        // next chunk's first __syncthreads protects scratch before restage
    }
    if (tid < 128) {
        assignv[r0 + tid] = bbk;
        if (assign16) assign16[r0 + tid] = (unsigned short)bbk;
    }
}

// ---------------------------------------------------------------------------
// Fast M-step, phase 1: 2048 blocks = 4 per cluster. Block b handles cluster
// b>>2, quarter b&3 of the rows. Deterministic (fixed tree, no atomics).
// ---------------------------------------------------------------------------
__global__ __launch_bounds__(256) void update_partial_kernel(
    const float* __restrict__ E, const unsigned short* __restrict__ assign16,
    float* __restrict__ ws_sums, int* __restrict__ ws_cnts)
{
    const int b   = blockIdx.x;
    const int k   = b >> 2;
    const int qtr = b & 3;

    __shared__ float acc[4][DD];
    __shared__ int   cnts[4];

    const int tid  = threadIdx.x;
    const int w    = tid >> 6;
    const int lane = tid & 63;

    float a0 = 0.f, a1 = 0.f;
    int cnt = 0;
    const int wbase = qtr * (NN / 4) + w * (NN / 16);

    for (int it = 0; it < (NN / 16) / 512; ++it) {   // 32 iters, 512 assigns each
        const int off = wbase + it * 512;
        uint4 p = *(const uint4*)&assign16[off + lane * 8];   // 8 u16
        unsigned v[4] = {p.x, p.y, p.z, p.w};
#pragma unroll
        for (int h = 0; h < 4; ++h) {
            int lo = (int)(v[h] & 0xffffu);
            int hi = (int)(v[h] >> 16);
            unsigned long long mlo = __ballot(lo == k);
            unsigned long long mhi = __ballot(hi == k);
            cnt += (int)__popcll(mlo) + (int)__popcll(mhi);
            while (mlo) {
                int b2 = __ffsll((long long)mlo) - 1; mlo &= mlo - 1;
                int row = off + b2 * 8 + h * 2;
                float2 e = *(const float2*)&E[(size_t)row * DD + lane * 2];
                a0 += e.x; a1 += e.y;
            }
            while (mhi) {
                int b2 = __ffsll((long long)mhi) - 1; mhi &= mhi - 1;
                int row = off + b2 * 8 + h * 2 + 1;
                float2 e = *(const float2*)&E[(size_t)row * DD + lane * 2];
                a0 += e.x; a1 += e.y;
            }
        }
    }
    acc[w][lane * 2]     = a0;
    acc[w][lane * 2 + 1] = a1;
    if (lane == 0) cnts[w] = cnt;
    __syncthreads();
    if (tid < DD)
        ws_sums[(size_t)b * DD + tid] = acc[0][tid] + acc[1][tid] + acc[2][tid] + acc[3][tid];
    if (tid == 0)
        ws_cnts[b] = cnts[0] + cnts[1] + cnts[2] + cnts[3];
}

// ---------------------------------------------------------------------------
// Fast M-step, phase 2: 512 blocks x 128 threads. Combine 4 partials, mean
// (keep old centroid if empty), L2-normalize in place.
// ---------------------------------------------------------------------------
__global__ __launch_bounds__(128) void update_combine_kernel(
    const float* __restrict__ ws_sums, const int* __restrict__ ws_cnts,
    float* __restrict__ C)
{
    const int k = blockIdx.x, t = threadIdx.x;
    __shared__ float red[2];
    const int w = t >> 6, lane = t & 63;

    float s = ws_sums[(size_t)(4 * k + 0) * DD + t]
            + ws_sums[(size_t)(4 * k + 1) * DD + t]
            + ws_sums[(size_t)(4 * k + 2) * DD + t]
            + ws_sums[(size_t)(4 * k + 3) * DD + t];
    int cnt = ws_cnts[4 * k] + ws_cnts[4 * k + 1] + ws_cnts[4 * k + 2] + ws_cnts[4 * k + 3];
    float m = (cnt > 0) ? s / (float)cnt : C[k * DD + t];

    float sq = m * m;
#pragma unroll
    for (int o = 32; o > 0; o >>= 1) sq += __shfl_down(sq, o, 64);
    if (lane == 0) red[w] = sq;
    __syncthreads();
    float nrm = fmaxf(sqrtf(red[0] + red[1]), 1e-12f);
    C[k * DD + t] = m / nrm;
}

// ---------------------------------------------------------------------------
// Fallback M-step (round-1 verified; no d_ws usage).
// ---------------------------------------------------------------------------
__global__ __launch_bounds__(256) void update_kernel(
    const float* __restrict__ E, const int* __restrict__ assignv,
    float* __restrict__ C)
{
    const int k = blockIdx.x;
    __shared__ float acc[4][DD];
    __shared__ int   cnts[4];
    __shared__ float red[4];

    const int tid  = threadIdx.x;
    const int w    = tid >> 6;
    const int lane = tid & 63;

    float a0 = 0.f, a1 = 0.f;
    int cnt = 0;
    const int per_wave = NN / 4;
    const int base = w * per_wave;

    for (int it = 0; it < per_wave / 256; ++it) {
        const int off = base + it * 256;
        int4 as = *(const int4*)&assignv[off + lane * 4];
        int av[4] = {as.x, as.y, as.z, as.w};
#pragma unroll
        for (int c = 0; c < 4; ++c) {
            unsigned long long m = __ballot(av[c] == k);
            cnt += (int)__popcll(m);
            while (m) {
                int b = __ffsll((long long)m) - 1;
                m &= m - 1;
                int r = off + b * 4 + c;
                float2 v = *(const float2*)&E[r * DD + lane * 2];
                a0 += v.x; a1 += v.y;
            }
        }
    }
    acc[w][lane * 2]     = a0;
    acc[w][lane * 2 + 1] = a1;
    if (lane == 0) cnts[w] = cnt;
    __syncthreads();

    float m = 0.f;
    const int ctot = cnts[0] + cnts[1] + cnts[2] + cnts[3];
    if (tid < DD) {
        float s = acc[0][tid] + acc[1][tid] + acc[2][tid] + acc[3][tid];
        m = (ctot > 0) ? s / (float)ctot : C[k * DD + tid];
    }
    float sq = m * m;
#pragma unroll
    for (int o = 32; o > 0; o >>= 1) sq += __shfl_down(sq, o, 64);
    if (lane == 0) red[w] = sq;
    __syncthreads();
    if (tid < DD) {
        float nrm = fmaxf(sqrtf(red[0] + red[1]), 1e-12f);
        C[k * DD + tid] = m / nrm;
    }
}

__global__ void finalize_kernel(float* __restrict__ out)
{
    int i = blockIdx.x * 256 + threadIdx.x;
    if (i < NN) {
        int a = ((const int*)out)[i];
        out[i] = (float)a;
    }
}

extern "C" void kernel_launch(void* const* d_in, const int* in_sizes, int n_in,
                              void* d_out, int out_size, void* d_ws, size_t ws_size,
                              hipStream_t stream)
{
    (void)in_sizes; (void)n_in; (void)out_size;

    const float* E  = (const float*)d_in[0];
    const float* C0 = (const float*)d_in[1];
    // num_iters (d_in[2]) is a fixed scalar = 5; hardcoded (graph-safe).

    float* out     = (float*)d_out;
    float* C       = out + NN;        // centroids in d_out tail
    int*   assignv = (int*)out;       // assign ints in d_out head

    const bool fast = (ws_size >= (size_t)WS_NEEDED);
    unsigned short* assign16 = fast ? (unsigned short*)d_ws : nullptr;
    float* ws_sums = fast ? (float*)((char*)d_ws + WS_SUMS_OFF) : nullptr;
    int*   ws_cnts = fast ? (int*)((char*)d_ws + WS_CNTS_OFF) : nullptr;
    // NOTE: every ws region is fully written each call before any read
    // (assign16 by assign_kernel, sums/cnts by update_partial) — poison-safe.

    hipMemcpyAsync(C, C0, (size_t)KK * DD * sizeof(float),
                   hipMemcpyDeviceToDevice, stream);

    for (int it = 0; it < NITER; ++it) {
        assign_kernel<<<NN / 128, 256, 0, stream>>>(E, C, assignv, assign16);
        if (fast) {
            update_partial_kernel<<<2048, 256, 0, stream>>>(E, assign16, ws_sums, ws_cnts);
            update_combine_kernel<<<KK, 128, 0, stream>>>(ws_sums, ws_cnts, C);
        } else {
            update_kernel<<<KK, 256, 0, stream>>>(E, assignv, C);
        }
    }
    finalize_kernel<<<(NN + 255) / 256, 256, 0, stream>>>(out);
}